// Round 15
// baseline (194.077 us; speedup 1.0000x reference)
//
#include <hip/hip_runtime.h>
#include <hip/hip_bf16.h>
#include <cstdint>
#include <cstddef>

namespace {
constexpr int B  = 8;
constexpr int S  = 768;
constexpr int V  = 384;
constexpr int A  = 384;
constexpr int H  = 8;
constexpr int D  = 64;
constexpr int HD = 512;
constexpr float SCALE = 0.125f;       // d^-0.5, d=64
constexpr float BBC   = 0.6f;
constexpr float NEGV  = -1000000000.0f;
constexpr size_t N_QH = (size_t)B * H * S * D;   // 3145728 (= 6144*512)
}

using short8 = __attribute__((ext_vector_type(8))) short;
using f32x4  = __attribute__((ext_vector_type(4))) float;

static __device__ __forceinline__ unsigned short f2bf(float f) {
  union { float f; unsigned int u; } v; v.f = f;
  unsigned int r = v.u + 0x7FFFu + ((v.u >> 16) & 1u);
  return (unsigned short)(r >> 16);
}
static __device__ __forceinline__ f32x4 mfma16(short8 a, short8 b, f32x4 c) {
  return __builtin_amdgcn_mfma_f32_16x16x32_bf16(a, b, c, 0, 0, 0);
}
static __device__ __forceinline__ short8 pack_bf8(float4 a, float4 b) {
  union { short8 s; uint4 u; } r;
  r.u.x = (unsigned)f2bf(a.x) | ((unsigned)f2bf(a.y) << 16);
  r.u.y = (unsigned)f2bf(a.z) | ((unsigned)f2bf(a.w) << 16);
  r.u.z = (unsigned)f2bf(b.x) | ((unsigned)f2bf(b.y) << 16);
  r.u.w = (unsigned)f2bf(b.z) | ((unsigned)f2bf(b.w) << 16);
  return r.s;
}
static __device__ __forceinline__ ushort4 pack_bf4(f32x4 a, float4 bi) {
  ushort4 r;
  r.x = f2bf(a[0] + bi.x); r.y = f2bf(a[1] + bi.y);
  r.z = f2bf(a[2] + bi.z); r.w = f2bf(a[3] + bi.w);
  return r;
}

// ---------------- prep_w: W[k][n] f32 -> WT bf16 [n][k] (RTN), 4 weights ----------
__global__ __launch_bounds__(256) void prep_w(
    const float* __restrict__ Wq, const float* __restrict__ Wk,
    const float* __restrict__ Wv, const float* __restrict__ Wo,
    unsigned short* __restrict__ wt)
{
  __shared__ float tile[64][68];
  const int id = blockIdx.x;           // 0..255
  const int z = id >> 6, tl = id & 63;
  const int k0 = (tl >> 3) * 64, n0 = (tl & 7) * 64;
  const float* W = (z == 0) ? Wq : (z == 1) ? Wk : (z == 2) ? Wv : Wo;
  unsigned short* WT = wt + (size_t)z * 262144;
  const int t = threadIdx.x;
#pragma unroll
  for (int u = 0; u < 4; ++u) {
    int idx = u * 256 + t;
    int r = idx >> 4, c4 = (idx & 15) * 4;
    *(float4*)&tile[r][c4] = *(const float4*)&W[(size_t)(k0 + r) * 512 + n0 + c4];
  }
  __syncthreads();
#pragma unroll
  for (int u = 0; u < 4; ++u) {
    int idx = u * 256 + t;
    int n = idx >> 4, kq = (idx & 15) * 4;
    unsigned int h0 = f2bf(tile[kq + 0][n]), h1 = f2bf(tile[kq + 1][n]);
    unsigned int h2 = f2bf(tile[kq + 2][n]), h3 = f2bf(tile[kq + 3][n]);
    *(uint2*)&WT[(size_t)(n0 + n) * 512 + k0 + kq] =
        make_uint2(h0 | (h1 << 16), h2 | (h3 << 16));
  }
}

// ---------------- qkv projections: 64x128 tile, X/W LDS-staged, 8 MFMA/barrier ---
// 1D grid 1152, chunked-XCD swizzle; outputs bf16 (q/k head-layout, v transposed)
__global__ __launch_bounds__(256) void qkv_mfma(
    const float* __restrict__ q, const float* __restrict__ k,
    const float* __restrict__ v, const unsigned short* __restrict__ wt,
    const float* __restrict__ bq, const float* __restrict__ bk,
    const float* __restrict__ bv,
    unsigned short* __restrict__ qh, unsigned short* __restrict__ kh,
    unsigned short* __restrict__ vhT)
{
  __shared__ unsigned short Bh[128][40];
  __shared__ unsigned short Ax[64][40];
  const int lin = ((blockIdx.x & 7) * 144) + (blockIdx.x >> 3);
  const int n0 = (lin & 3) * 128;
  const int gidx = lin >> 2;          // 0..287
  const int mt = gidx % 96, z = gidx / 96;
  const int m0 = mt * 64;
  const float* X = (z == 0) ? q : (z == 1) ? k : v;
  const unsigned short* WT = wt + (size_t)z * 262144;
  const float* bias = (z == 0) ? bq : (z == 1) ? bk : bv;
  const int t = threadIdx.x, w = t >> 6, lane = t & 63;
  const int l15 = lane & 15, g = lane >> 4;
  const int bb = m0 / S;
  f32x4 acc[8] = {};

  const int srow = t >> 2, skq = (t & 3) * 8;
  for (int k0 = 0; k0 < 512; k0 += 32) {
    float4 x0 = *(const float4*)&X[(size_t)(m0 + srow) * 512 + k0 + skq];
    float4 x1 = *(const float4*)&X[(size_t)(m0 + srow) * 512 + k0 + skq + 4];
    short8 wr0 = *(const short8*)&WT[(size_t)(n0 + srow) * 512 + k0 + skq];
    short8 wr1 = *(const short8*)&WT[(size_t)(n0 + 64 + srow) * 512 + k0 + skq];
    __syncthreads();
    *(short8*)&Ax[srow][skq] = pack_bf8(x0, x1);
    *(short8*)&Bh[srow][skq] = wr0;
    *(short8*)&Bh[64 + srow][skq] = wr1;
    __syncthreads();
    if (z != 2) {
      short8 xfrag = *(short8*)&Ax[w * 16 + l15][g * 8];
#pragma unroll
      for (int tn = 0; tn < 8; ++tn) {
        short8 wfrag = *(short8*)&Bh[tn * 16 + l15][g * 8];
        acc[tn] = mfma16(wfrag, xfrag, acc[tn]);   // D: lane=X row, reg=W col
      }
    } else {  // v: swapped operands -> D[n][m], lanes along s -> coalesced vhT
      short8 wh0 = *(short8*)&Bh[(w * 2 + 0) * 16 + l15][g * 8];
      short8 wh1 = *(short8*)&Bh[(w * 2 + 1) * 16 + l15][g * 8];
#pragma unroll
      for (int tm = 0; tm < 4; ++tm) {
        short8 xf = *(short8*)&Ax[tm * 16 + l15][g * 8];
        acc[tm]     = mfma16(wh0, xf, acc[tm]);
        acc[4 + tm] = mfma16(wh1, xf, acc[4 + tm]);
      }
    }
  }

  if (z != 2) {
    unsigned short* Y = (z == 0) ? qh : kh;
    const int s = m0 + w * 16 + l15 - bb * S;
#pragma unroll
    for (int tn = 0; tn < 8; ++tn) {
      const int n = n0 + tn * 16 + g * 4;
      const int h = n >> 6, d0 = n & 63;
      float4 bi4 = *(const float4*)&bias[n];
      *(ushort4*)&Y[((size_t)(bb * H + h) * S + s) * D + d0] = pack_bf4(acc[tn], bi4);
    }
  } else {
#pragma unroll
    for (int j = 0; j < 2; ++j)
#pragma unroll
      for (int tm = 0; tm < 4; ++tm) {
        const int mcol = m0 + tm * 16 + l15;
        const int s = mcol - bb * S;
#pragma unroll
        for (int r = 0; r < 4; ++r) {
          const int n = n0 + (w * 2 + j) * 16 + g * 4 + r;
          const int h = n >> 6, d = n & 63;
          vhT[((size_t)(bb * H + h) * D + d) * S + s] = f2bf(acc[j * 4 + tm][r] + bias[n]);
        }
      }
  }
}

// ---------------- fused attention: 16 rows x 768 cols per 4-wave block ----------
// column-interleaved tiles; __launch_bounds__(256,5) -> target 5 blocks/CU
__global__ __launch_bounds__(256, 5) void fused_attn(
    const unsigned short* __restrict__ qh, const unsigned short* __restrict__ kh,
    const unsigned short* __restrict__ vhT,
    const float* __restrict__ mask, const float* __restrict__ depth_value,
    const float* __restrict__ mean_depth,
    float* __restrict__ att_score, float* __restrict__ att_map,
    unsigned short* __restrict__ ctx, float* __restrict__ md_rows)
{
  __shared__ unsigned short Ps[16][768];   // XOR-swizzled bf16 P tile (24 KB)
  __shared__ float mcol[768];
  __shared__ float dvcol[384];
  __shared__ float pmax[16][4];
  __shared__ float psum[16][4];
  __shared__ float psem[16][4];
  __shared__ float asmd[16][4];
  __shared__ float mxA[16], rdA[16], drefsA[16], mrwA[16];

  const int id = blockIdx.x;
  const int rest = id >> 3;
  const int rt = rest % 48;
  const int bh = (id & 7) + 8 * (rest / 48);
  const int b = bh >> 3, b0 = b >> 2;
  const int r0 = rt * 16;
  const int t = threadIdx.x;
  const int w = t >> 6;
  const int lane = t & 63;
  const int l15 = lane & 15, g = lane >> 4;
  const bool avblk = (r0 >= V);

  for (int j = t; j < 768; j += 256) mcol[j] = mask[(size_t)b * S + j];
  for (int j = t; j < 384; j += 256) dvcol[j] = depth_value[(size_t)b0 * V + j];
  if (t < 16) {
    const int row = r0 + t;
    drefsA[t] = (row < V) ? depth_value[(size_t)b0 * V + row]
                          : mean_depth[(size_t)b * A + (row - V)];
    mrwA[t] = mask[(size_t)b * S + row];
  }

  // Q fragments (single bf16), rows r0..r0+15
  short8 qf[2];
#pragma unroll
  for (int ks = 0; ks < 2; ++ks)
    qf[ks] = *(const short8*)&qh[((size_t)bh * S + r0 + l15) * D + ks * 32 + g * 8];

  // ---- scores: 1-pass bf16 MFMA; tile tn at cols [tn*64 + w*16, +16) ----
  f32x4 acc[12] = {};
#pragma unroll
  for (int tn = 0; tn < 12; ++tn) {
    const int col = tn * 64 + w * 16 + l15;
#pragma unroll
    for (int ks = 0; ks < 2; ++ks) {
      short8 kf = *(const short8*)&kh[((size_t)bh * S + col) * D + ks * 32 + g * 8];
      acc[tn] = mfma16(qf[ks], kf, acc[tn]);
    }
  }
  __syncthreads();   // LDS stage ready

  // ---- epilogue: scale + AV stats (pre-bias, amx=0) + depth bias + mask ----
#pragma unroll
  for (int r = 0; r < 4; ++r) {
    const int lrow = g * 4 + r;
    const int row = r0 + lrow;
    const float mr = mrwA[lrow];
    const float dref = drefsA[lrow];
    float* srow = &att_score[((size_t)bh * S + row) * S];
    float se = 0.f, sem = 0.f, smd = 0.f;
#pragma unroll
    for (int tn = 0; tn < 12; ++tn) {
      const int col = tn * 64 + w * 16 + l15;
      const float mc = mcol[col];
      float x = acc[tn][r] * SCALE;
      if (tn < 6) {   // cols < V
        const float dv = dvcol[col];
        if (avblk) {
          float pm = mr * mc;
          float e = (pm > 0.f) ? __expf(x) : 0.f;
          se += e; sem += e * pm; smd += e * pm * dv;
        }
        float gg = __expf(-fabsf(dref - dv)) - BBC;
        float bb2 = fabsf(x) * gg;
        if (row == col) bb2 = 0.f;
        x += bb2;
      }
      x = (mr * mc > 0.f) ? x : NEGV;
      __builtin_nontemporal_store(x, &srow[col]);
      acc[tn][r] = x;
    }
    if (avblk) {
#pragma unroll
      for (int o = 1; o < 16; o <<= 1) {
        se += __shfl_xor(se, o, 16);
        sem += __shfl_xor(sem, o, 16);
        smd += __shfl_xor(smd, o, 16);
      }
      if (l15 == 0) { psum[lrow][w] = se; psem[lrow][w] = sem; asmd[lrow][w] = smd; }
    }
  }

  // ---- main row max partials ----
#pragma unroll
  for (int r = 0; r < 4; ++r) {
    float v = NEGV;
#pragma unroll
    for (int tn = 0; tn < 12; ++tn) v = fmaxf(v, acc[tn][r]);
#pragma unroll
    for (int o = 1; o < 16; o <<= 1) v = fmaxf(v, __shfl_xor(v, o, 16));
    if (l15 == 0) pmax[g * 4 + r][w] = v;
  }
  __syncthreads();
  if (t < 16) {
    mxA[t] = fmaxf(fmaxf(pmax[t][0], pmax[t][1]), fmaxf(pmax[t][2], pmax[t][3]));
    if (avblk) {
      float se = psum[t][0] + psum[t][1] + psum[t][2] + psum[t][3];
      float sem = psem[t][0] + psem[t][1] + psem[t][2] + psem[t][3];
      float smd = asmd[t][0] + asmd[t][1] + asmd[t][2] + asmd[t][3];
      md_rows[(size_t)bh * A + (r0 + t - V)] = smd / (sem + 1e-13f * se);
    }
  }
  __syncthreads();

  // ---- main softmax sums ----
#pragma unroll
  for (int r = 0; r < 4; ++r) {
    const int lrow = g * 4 + r;
    const float mx = mxA[lrow];
    const float mr = mrwA[lrow];
    float se = 0.f, sem = 0.f;
#pragma unroll
    for (int tn = 0; tn < 12; ++tn) {
      const int col = tn * 64 + w * 16 + l15;
      float e = __expf(acc[tn][r] - mx);
      acc[tn][r] = e;
      se += e; sem += e * (mr * mcol[col]);
    }
#pragma unroll
    for (int o = 1; o < 16; o <<= 1) {
      se += __shfl_xor(se, o, 16);
      sem += __shfl_xor(sem, o, 16);
    }
    if (l15 == 0) { psum[lrow][w] = se; psem[lrow][w] = sem; }
  }
  __syncthreads();
  if (t < 16) {
    float se = psum[t][0] + psum[t][1] + psum[t][2] + psum[t][3];
    float sem = psem[t][0] + psem[t][1] + psem[t][2] + psem[t][3];
    rdA[t] = 1.f / (sem + 1e-13f * se);
  }
  __syncthreads();

  // ---- p writeout + swizzled bf16 P ----
#pragma unroll
  for (int r = 0; r < 4; ++r) {
    const int lrow = g * 4 + r;
    const int row = r0 + lrow;
    const float rden = rdA[lrow];
    const float mr = mrwA[lrow];
    float* prow = &att_map[((size_t)bh * S + row) * S];
    const int swz = (lrow & 7) << 4;
#pragma unroll
    for (int tn = 0; tn < 12; ++tn) {
      const int col = tn * 64 + w * 16 + l15;
      float p = acc[tn][r] * (mr * mcol[col]) * rden;
      __builtin_nontemporal_store(p, &prow[col]);
      Ps[lrow][col ^ swz] = f2bf(p);
    }
  }
  __syncthreads();

  // ---- PV: ctx(16x64) = P(16x768) @ V(768x64); wave w owns d block [w*16,w*16+16) ----
  {
    const int aswz = (l15 & 7) << 4;
    f32x4 pacc = {};
    const unsigned short* vcol = &vhT[((size_t)bh * D + w * 16 + l15) * S];
#pragma unroll 8
    for (int kk = 0; kk < 24; ++kk) {
      short8 a = *(short8*)&Ps[l15][(kk * 32 + g * 8) ^ aswz];
      short8 bv = *(const short8*)&vcol[kk * 32 + g * 8];
      pacc = mfma16(a, bv, pacc);
    }
#pragma unroll
    for (int r = 0; r < 4; ++r) {
      const int row = r0 + g * 4 + r;
      ctx[((size_t)bh * S + row) * D + w * 16 + l15] = f2bf(pacc[r]);
    }
  }
}

// ---------------- out projection (+ fused md finalize) ----------------
// 1D grid 776: id<768 -> GEMM tile (chunked-XCD swizzle); id>=768 -> md for b=id-768
__global__ __launch_bounds__(256) void gemm_out(
    const unsigned short* __restrict__ Xb, const unsigned short* __restrict__ WT,
    const float* __restrict__ bias, float* __restrict__ Yf,
    const float* __restrict__ md_rows, const float* __restrict__ va_a_mask,
    float* __restrict__ md_out)
{
  const int t = threadIdx.x;
  if (blockIdx.x >= 768) {
    __shared__ float red0[256];
    __shared__ float red1[256];
    const int b = blockIdx.x - 768;
    float s1 = 0.f, s2 = 0.f;
    for (int u = t; u < H * A; u += 256) s1 += md_rows[(size_t)b * H * A + u];
    for (int u = t; u < A; u += 256) s2 += va_a_mask[(size_t)b * A + u];
    red0[t] = s1; red1[t] = s2;
    __syncthreads();
    for (int o = 128; o > 0; o >>= 1) {
      if (t < o) { red0[t] += red0[t + o]; red1[t] += red1[t + o]; }
      __syncthreads();
    }
    const float val = red0[0] / ((float)H * red1[0]);
    for (int u = t; u < A; u += 256) md_out[(size_t)b * A + u] = val;
    return;
  }
  __shared__ unsigned short Bh[64][40];
  const int lin = ((blockIdx.x & 7) * 96) + (blockIdx.x >> 3);
  const int n0 = (lin & 7) * 64;
  const int m0 = (lin >> 3) * 64;
  const int w = t >> 6, lane = t & 63;
  const int l15 = lane & 15, g = lane >> 4;
  const int bb = m0 / S;
  f32x4 acc[4] = {};
  const int srow = t >> 2, skq = (t & 3) * 8;
  const int s = m0 + w * 16 + l15 - bb * S;
  for (int k0 = 0; k0 < 512; k0 += 32) {
    __syncthreads();
    *(short8*)&Bh[srow][skq] = *(const short8*)&WT[(size_t)(n0 + srow) * 512 + k0 + skq];
    __syncthreads();
    const int h = k0 >> 6, d = (k0 & 63) + g * 8;
    short8 ah = *(const short8*)&Xb[((size_t)(bb * H + h) * S + s) * D + d];
#pragma unroll
    for (int tn = 0; tn < 4; ++tn) {
      short8 bh_ = *(short8*)&Bh[tn * 16 + l15][g * 8];
      acc[tn] = mfma16(ah, bh_, acc[tn]);
    }
  }
#pragma unroll
  for (int tn = 0; tn < 4; ++tn) {
    const int c = n0 + tn * 16 + l15;
    const float bi = bias[c];
#pragma unroll
    for (int r = 0; r < 4; ++r) {
      const int m = m0 + w * 16 + g * 4 + r;
      Yf[(size_t)m * 512 + c] = acc[tn][r] + bi;
    }
  }
}

extern "C" void kernel_launch(void* const* d_in, const int* in_sizes, int n_in,
                              void* d_out, int out_size, void* d_ws, size_t ws_size,
                              hipStream_t stream) {
  const float* q           = (const float*)d_in[0];
  const float* k           = (const float*)d_in[1];
  const float* v           = (const float*)d_in[2];
  const float* mask        = (const float*)d_in[3];
  const float* depth_value = (const float*)d_in[4];
  const float* va_a_mask   = (const float*)d_in[7];
  const float* mean_depth  = (const float*)d_in[8];
  const float* Wq = (const float*)d_in[9];
  const float* bq = (const float*)d_in[10];
  const float* Wk = (const float*)d_in[11];
  const float* bk = (const float*)d_in[12];
  const float* Wv = (const float*)d_in[13];
  const float* bv = (const float*)d_in[14];
  const float* Wo = (const float*)d_in[15];
  const float* bo = (const float*)d_in[16];

  unsigned short* wsu = (unsigned short*)d_ws;
  unsigned short* qh  = wsu;                 // aliased by ctx after q-frag reads
  unsigned short* kh  = wsu + N_QH;
  unsigned short* vhT = wsu + 2 * N_QH;
  unsigned short* ctx = qh;                  // alias (per-row ownership matches)
  unsigned short* wt  = wsu + 3 * N_QH;      // 4 weights x 262144 bf16
  float* md_rows = (float*)(wsu + 3 * N_QH + 4 * 262144);

  float* out       = (float*)d_out;
  float* att_score = out + (size_t)B * S * HD;
  float* att_map   = att_score + (size_t)B * H * S * S;
  float* md_out    = att_map + (size_t)B * H * S * S;

  prep_w<<<256, 256, 0, stream>>>(Wq, Wk, Wv, Wo, wt);
  qkv_mfma<<<1152, 256, 0, stream>>>(q, k, v, wt, bq, bk, bv, qh, kh, vhT);
  fused_attn<<<3072, 256, 0, stream>>>(qh, kh, vhT, mask, depth_value, mean_depth,
                                       att_score, att_map, ctx, md_rows);
  gemm_out<<<776, 256, 0, stream>>>(ctx, wt + 3 * 262144, bo, out,
                                    md_rows, va_a_mask, md_out);
}

// Round 16
// 152.535 us; speedup vs baseline: 1.2723x; 1.2723x over previous
//
#include <hip/hip_runtime.h>
#include <hip/hip_bf16.h>
#include <cstdint>
#include <cstddef>

namespace {
constexpr int B  = 8;
constexpr int S  = 768;
constexpr int V  = 384;
constexpr int A  = 384;
constexpr int H  = 8;
constexpr int D  = 64;
constexpr int HD = 512;
constexpr float SCALE = 0.125f;       // d^-0.5, d=64
constexpr float BBC   = 0.6f;
constexpr float NEGV  = -1000000000.0f;
constexpr size_t N_QH = (size_t)B * H * S * D;   // 3145728 (= 6144*512)
}

using short8 = __attribute__((ext_vector_type(8))) short;
using f32x4  = __attribute__((ext_vector_type(4))) float;

static __device__ __forceinline__ unsigned short f2bf(float f) {
  union { float f; unsigned int u; } v; v.f = f;
  unsigned int r = v.u + 0x7FFFu + ((v.u >> 16) & 1u);
  return (unsigned short)(r >> 16);
}
static __device__ __forceinline__ f32x4 mfma16(short8 a, short8 b, f32x4 c) {
  return __builtin_amdgcn_mfma_f32_16x16x32_bf16(a, b, c, 0, 0, 0);
}
static __device__ __forceinline__ short8 pack_bf8(float4 a, float4 b) {
  union { short8 s; uint4 u; } r;
  r.u.x = (unsigned)f2bf(a.x) | ((unsigned)f2bf(a.y) << 16);
  r.u.y = (unsigned)f2bf(a.z) | ((unsigned)f2bf(a.w) << 16);
  r.u.z = (unsigned)f2bf(b.x) | ((unsigned)f2bf(b.y) << 16);
  r.u.w = (unsigned)f2bf(b.z) | ((unsigned)f2bf(b.w) << 16);
  return r.s;
}
static __device__ __forceinline__ ushort4 pack_bf4(f32x4 a, float4 bi) {
  ushort4 r;
  r.x = f2bf(a[0] + bi.x); r.y = f2bf(a[1] + bi.y);
  r.z = f2bf(a[2] + bi.z); r.w = f2bf(a[3] + bi.w);
  return r;
}

// ---------------- prep_w: W[k][n] f32 -> WT bf16 [n][k] (RTN), 4 weights ----------
__global__ __launch_bounds__(256) void prep_w(
    const float* __restrict__ Wq, const float* __restrict__ Wk,
    const float* __restrict__ Wv, const float* __restrict__ Wo,
    unsigned short* __restrict__ wt)
{
  __shared__ float tile[64][68];
  const int id = blockIdx.x;           // 0..255
  const int z = id >> 6, tl = id & 63;
  const int k0 = (tl >> 3) * 64, n0 = (tl & 7) * 64;
  const float* W = (z == 0) ? Wq : (z == 1) ? Wk : (z == 2) ? Wv : Wo;
  unsigned short* WT = wt + (size_t)z * 262144;
  const int t = threadIdx.x;
#pragma unroll
  for (int u = 0; u < 4; ++u) {
    int idx = u * 256 + t;
    int r = idx >> 4, c4 = (idx & 15) * 4;
    *(float4*)&tile[r][c4] = *(const float4*)&W[(size_t)(k0 + r) * 512 + n0 + c4];
  }
  __syncthreads();
#pragma unroll
  for (int u = 0; u < 4; ++u) {
    int idx = u * 256 + t;
    int n = idx >> 4, kq = (idx & 15) * 4;
    unsigned int h0 = f2bf(tile[kq + 0][n]), h1 = f2bf(tile[kq + 1][n]);
    unsigned int h2 = f2bf(tile[kq + 2][n]), h3 = f2bf(tile[kq + 3][n]);
    *(uint2*)&WT[(size_t)(n0 + n) * 512 + k0 + kq] =
        make_uint2(h0 | (h1 << 16), h2 | (h3 << 16));
  }
}

// ---------------- qkv projections: 64x128 tile, X/W LDS-staged, 8 MFMA/barrier ---
// 1D grid 1152, chunked-XCD swizzle; outputs bf16 (q/k head-layout, v transposed)
__global__ __launch_bounds__(256) void qkv_mfma(
    const float* __restrict__ q, const float* __restrict__ k,
    const float* __restrict__ v, const unsigned short* __restrict__ wt,
    const float* __restrict__ bq, const float* __restrict__ bk,
    const float* __restrict__ bv,
    unsigned short* __restrict__ qh, unsigned short* __restrict__ kh,
    unsigned short* __restrict__ vhT)
{
  __shared__ unsigned short Bh[128][40];
  __shared__ unsigned short Ax[64][40];
  const int lin = ((blockIdx.x & 7) * 144) + (blockIdx.x >> 3);
  const int n0 = (lin & 3) * 128;
  const int gidx = lin >> 2;          // 0..287
  const int mt = gidx % 96, z = gidx / 96;
  const int m0 = mt * 64;
  const float* X = (z == 0) ? q : (z == 1) ? k : v;
  const unsigned short* WT = wt + (size_t)z * 262144;
  const float* bias = (z == 0) ? bq : (z == 1) ? bk : bv;
  const int t = threadIdx.x, w = t >> 6, lane = t & 63;
  const int l15 = lane & 15, g = lane >> 4;
  const int bb = m0 / S;
  f32x4 acc[8] = {};

  const int srow = t >> 2, skq = (t & 3) * 8;
  for (int k0 = 0; k0 < 512; k0 += 32) {
    float4 x0 = *(const float4*)&X[(size_t)(m0 + srow) * 512 + k0 + skq];
    float4 x1 = *(const float4*)&X[(size_t)(m0 + srow) * 512 + k0 + skq + 4];
    short8 wr0 = *(const short8*)&WT[(size_t)(n0 + srow) * 512 + k0 + skq];
    short8 wr1 = *(const short8*)&WT[(size_t)(n0 + 64 + srow) * 512 + k0 + skq];
    __syncthreads();
    *(short8*)&Ax[srow][skq] = pack_bf8(x0, x1);
    *(short8*)&Bh[srow][skq] = wr0;
    *(short8*)&Bh[64 + srow][skq] = wr1;
    __syncthreads();
    if (z != 2) {
      short8 xfrag = *(short8*)&Ax[w * 16 + l15][g * 8];
#pragma unroll
      for (int tn = 0; tn < 8; ++tn) {
        short8 wfrag = *(short8*)&Bh[tn * 16 + l15][g * 8];
        acc[tn] = mfma16(wfrag, xfrag, acc[tn]);   // D: lane=X row, reg=W col
      }
    } else {  // v: swapped operands -> D[n][m], lanes along s -> coalesced vhT
      short8 wh0 = *(short8*)&Bh[(w * 2 + 0) * 16 + l15][g * 8];
      short8 wh1 = *(short8*)&Bh[(w * 2 + 1) * 16 + l15][g * 8];
#pragma unroll
      for (int tm = 0; tm < 4; ++tm) {
        short8 xf = *(short8*)&Ax[tm * 16 + l15][g * 8];
        acc[tm]     = mfma16(wh0, xf, acc[tm]);
        acc[4 + tm] = mfma16(wh1, xf, acc[4 + tm]);
      }
    }
  }

  if (z != 2) {
    unsigned short* Y = (z == 0) ? qh : kh;
    const int s = m0 + w * 16 + l15 - bb * S;
#pragma unroll
    for (int tn = 0; tn < 8; ++tn) {
      const int n = n0 + tn * 16 + g * 4;
      const int h = n >> 6, d0 = n & 63;
      float4 bi4 = *(const float4*)&bias[n];
      *(ushort4*)&Y[((size_t)(bb * H + h) * S + s) * D + d0] = pack_bf4(acc[tn], bi4);
    }
  } else {
#pragma unroll
    for (int j = 0; j < 2; ++j)
#pragma unroll
      for (int tm = 0; tm < 4; ++tm) {
        const int mcol = m0 + tm * 16 + l15;
        const int s = mcol - bb * S;
#pragma unroll
        for (int r = 0; r < 4; ++r) {
          const int n = n0 + (w * 2 + j) * 16 + g * 4 + r;
          const int h = n >> 6, d = n & 63;
          vhT[((size_t)(bb * H + h) * D + d) * S + s] = f2bf(acc[j * 4 + tm][r] + bias[n]);
        }
      }
  }
}

// ---------------- fused attention: 16 rows x 768 cols per 4-wave block ----------
// column-interleaved tiles: tile tn -> cols [tn*64 + w*16, +16) => balanced bias work
__global__ __launch_bounds__(256, 4) void fused_attn(
    const unsigned short* __restrict__ qh, const unsigned short* __restrict__ kh,
    const unsigned short* __restrict__ vhT,
    const float* __restrict__ mask, const float* __restrict__ depth_value,
    const float* __restrict__ mean_depth,
    float* __restrict__ att_score, float* __restrict__ att_map,
    unsigned short* __restrict__ ctx, float* __restrict__ md_rows)
{
  __shared__ unsigned short Ps[16][768];   // XOR-swizzled bf16 P tile (24 KB)
  __shared__ float mcol[768];
  __shared__ float dvcol[384];
  __shared__ float pmax[16][4];
  __shared__ float psum[16][4];
  __shared__ float psem[16][4];
  __shared__ float asmd[16][4];
  __shared__ float mxA[16], rdA[16], drefsA[16], mrwA[16];

  const int id = blockIdx.x;
  const int rest = id >> 3;
  const int rt = rest % 48;
  const int bh = (id & 7) + 8 * (rest / 48);
  const int b = bh >> 3, b0 = b >> 2;
  const int r0 = rt * 16;
  const int t = threadIdx.x;
  const int w = t >> 6;
  const int lane = t & 63;
  const int l15 = lane & 15, g = lane >> 4;
  const bool avblk = (r0 >= V);

  for (int j = t; j < 768; j += 256) mcol[j] = mask[(size_t)b * S + j];
  for (int j = t; j < 384; j += 256) dvcol[j] = depth_value[(size_t)b0 * V + j];
  if (t < 16) {
    const int row = r0 + t;
    drefsA[t] = (row < V) ? depth_value[(size_t)b0 * V + row]
                          : mean_depth[(size_t)b * A + (row - V)];
    mrwA[t] = mask[(size_t)b * S + row];
  }

  // Q fragments (single bf16), rows r0..r0+15
  short8 qf[2];
#pragma unroll
  for (int ks = 0; ks < 2; ++ks)
    qf[ks] = *(const short8*)&qh[((size_t)bh * S + r0 + l15) * D + ks * 32 + g * 8];

  // ---- scores: 1-pass bf16 MFMA; tile tn at cols [tn*64 + w*16, +16) ----
  f32x4 acc[12] = {};
#pragma unroll
  for (int tn = 0; tn < 12; ++tn) {
    const int col = tn * 64 + w * 16 + l15;
#pragma unroll
    for (int ks = 0; ks < 2; ++ks) {
      short8 kf = *(const short8*)&kh[((size_t)bh * S + col) * D + ks * 32 + g * 8];
      acc[tn] = mfma16(qf[ks], kf, acc[tn]);
    }
  }
  __syncthreads();   // LDS stage ready

  // ---- epilogue: scale + AV stats (pre-bias, amx=0) + depth bias + mask ----
#pragma unroll
  for (int r = 0; r < 4; ++r) {
    const int lrow = g * 4 + r;
    const int row = r0 + lrow;
    const float mr = mrwA[lrow];
    const float dref = drefsA[lrow];
    float* srow = &att_score[((size_t)bh * S + row) * S];
    float se = 0.f, sem = 0.f, smd = 0.f;
#pragma unroll
    for (int tn = 0; tn < 12; ++tn) {
      const int col = tn * 64 + w * 16 + l15;
      const float mc = mcol[col];
      float x = acc[tn][r] * SCALE;
      if (tn < 6) {   // cols < V
        const float dv = dvcol[col];
        if (avblk) {
          float pm = mr * mc;
          float e = (pm > 0.f) ? __expf(x) : 0.f;
          se += e; sem += e * pm; smd += e * pm * dv;
        }
        float gg = __expf(-fabsf(dref - dv)) - BBC;
        float bb2 = fabsf(x) * gg;
        if (row == col) bb2 = 0.f;
        x += bb2;
      }
      x = (mr * mc > 0.f) ? x : NEGV;
      __builtin_nontemporal_store(x, &srow[col]);
      acc[tn][r] = x;
    }
    if (avblk) {
#pragma unroll
      for (int o = 1; o < 16; o <<= 1) {
        se += __shfl_xor(se, o, 16);
        sem += __shfl_xor(sem, o, 16);
        smd += __shfl_xor(smd, o, 16);
      }
      if (l15 == 0) { psum[lrow][w] = se; psem[lrow][w] = sem; asmd[lrow][w] = smd; }
    }
  }

  // ---- main row max partials ----
#pragma unroll
  for (int r = 0; r < 4; ++r) {
    float v = NEGV;
#pragma unroll
    for (int tn = 0; tn < 12; ++tn) v = fmaxf(v, acc[tn][r]);
#pragma unroll
    for (int o = 1; o < 16; o <<= 1) v = fmaxf(v, __shfl_xor(v, o, 16));
    if (l15 == 0) pmax[g * 4 + r][w] = v;
  }
  __syncthreads();
  if (t < 16) {
    mxA[t] = fmaxf(fmaxf(pmax[t][0], pmax[t][1]), fmaxf(pmax[t][2], pmax[t][3]));
    if (avblk) {
      float se = psum[t][0] + psum[t][1] + psum[t][2] + psum[t][3];
      float sem = psem[t][0] + psem[t][1] + psem[t][2] + psem[t][3];
      float smd = asmd[t][0] + asmd[t][1] + asmd[t][2] + asmd[t][3];
      md_rows[(size_t)bh * A + (r0 + t - V)] = smd / (sem + 1e-13f * se);
    }
  }
  __syncthreads();

  // ---- main softmax sums ----
#pragma unroll
  for (int r = 0; r < 4; ++r) {
    const int lrow = g * 4 + r;
    const float mx = mxA[lrow];
    const float mr = mrwA[lrow];
    float se = 0.f, sem = 0.f;
#pragma unroll
    for (int tn = 0; tn < 12; ++tn) {
      const int col = tn * 64 + w * 16 + l15;
      float e = __expf(acc[tn][r] - mx);
      acc[tn][r] = e;
      se += e; sem += e * (mr * mcol[col]);
    }
#pragma unroll
    for (int o = 1; o < 16; o <<= 1) {
      se += __shfl_xor(se, o, 16);
      sem += __shfl_xor(sem, o, 16);
    }
    if (l15 == 0) { psum[lrow][w] = se; psem[lrow][w] = sem; }
  }
  __syncthreads();
  if (t < 16) {
    float se = psum[t][0] + psum[t][1] + psum[t][2] + psum[t][3];
    float sem = psem[t][0] + psem[t][1] + psem[t][2] + psem[t][3];
    rdA[t] = 1.f / (sem + 1e-13f * se);
  }
  __syncthreads();

  // ---- p writeout + swizzled bf16 P ----
#pragma unroll
  for (int r = 0; r < 4; ++r) {
    const int lrow = g * 4 + r;
    const int row = r0 + lrow;
    const float rden = rdA[lrow];
    const float mr = mrwA[lrow];
    float* prow = &att_map[((size_t)bh * S + row) * S];
    const int swz = (lrow & 7) << 4;
#pragma unroll
    for (int tn = 0; tn < 12; ++tn) {
      const int col = tn * 64 + w * 16 + l15;
      float p = acc[tn][r] * (mr * mcol[col]) * rden;
      __builtin_nontemporal_store(p, &prow[col]);
      Ps[lrow][col ^ swz] = f2bf(p);
    }
  }
  __syncthreads();

  // ---- PV: ctx(16x64) = P(16x768) @ V(768x64); wave w owns d block [w*16,w*16+16) ----
  {
    const int aswz = (l15 & 7) << 4;
    f32x4 pacc = {};
    const unsigned short* vcol = &vhT[((size_t)bh * D + w * 16 + l15) * S];
#pragma unroll 8
    for (int kk = 0; kk < 24; ++kk) {
      short8 a = *(short8*)&Ps[l15][(kk * 32 + g * 8) ^ aswz];
      short8 bv = *(const short8*)&vcol[kk * 32 + g * 8];
      pacc = mfma16(a, bv, pacc);
    }
#pragma unroll
    for (int r = 0; r < 4; ++r) {
      const int row = r0 + g * 4 + r;
      ctx[((size_t)bh * S + row) * D + w * 16 + l15] = f2bf(pacc[r]);
    }
  }
}

// ---------------- out projection (+ fused md finalize) ----------------
// 1D grid 776: id<768 -> GEMM tile (chunked-XCD swizzle); id>=768 -> md for b=id-768
__global__ __launch_bounds__(256) void gemm_out(
    const unsigned short* __restrict__ Xb, const unsigned short* __restrict__ WT,
    const float* __restrict__ bias, float* __restrict__ Yf,
    const float* __restrict__ md_rows, const float* __restrict__ va_a_mask,
    float* __restrict__ md_out)
{
  const int t = threadIdx.x;
  if (blockIdx.x >= 768) {
    __shared__ float red0[256];
    __shared__ float red1[256];
    const int b = blockIdx.x - 768;
    float s1 = 0.f, s2 = 0.f;
    for (int u = t; u < H * A; u += 256) s1 += md_rows[(size_t)b * H * A + u];
    for (int u = t; u < A; u += 256) s2 += va_a_mask[(size_t)b * A + u];
    red0[t] = s1; red1[t] = s2;
    __syncthreads();
    for (int o = 128; o > 0; o >>= 1) {
      if (t < o) { red0[t] += red0[t + o]; red1[t] += red1[t + o]; }
      __syncthreads();
    }
    const float val = red0[0] / ((float)H * red1[0]);
    for (int u = t; u < A; u += 256) md_out[(size_t)b * A + u] = val;
    return;
  }
  __shared__ unsigned short Bh[64][40];
  const int lin = ((blockIdx.x & 7) * 96) + (blockIdx.x >> 3);
  const int n0 = (lin & 7) * 64;
  const int m0 = (lin >> 3) * 64;
  const int w = t >> 6, lane = t & 63;
  const int l15 = lane & 15, g = lane >> 4;
  const int bb = m0 / S;
  f32x4 acc[4] = {};
  const int srow = t >> 2, skq = (t & 3) * 8;
  const int s = m0 + w * 16 + l15 - bb * S;
  for (int k0 = 0; k0 < 512; k0 += 32) {
    __syncthreads();
    *(short8*)&Bh[srow][skq] = *(const short8*)&WT[(size_t)(n0 + srow) * 512 + k0 + skq];
    __syncthreads();
    const int h = k0 >> 6, d = (k0 & 63) + g * 8;
    short8 ah = *(const short8*)&Xb[((size_t)(bb * H + h) * S + s) * D + d];
#pragma unroll
    for (int tn = 0; tn < 4; ++tn) {
      short8 bh_ = *(short8*)&Bh[tn * 16 + l15][g * 8];
      acc[tn] = mfma16(ah, bh_, acc[tn]);
    }
  }
#pragma unroll
  for (int tn = 0; tn < 4; ++tn) {
    const int c = n0 + tn * 16 + l15;
    const float bi = bias[c];
#pragma unroll
    for (int r = 0; r < 4; ++r) {
      const int m = m0 + w * 16 + g * 4 + r;
      Yf[(size_t)m * 512 + c] = acc[tn][r] + bi;
    }
  }
}

extern "C" void kernel_launch(void* const* d_in, const int* in_sizes, int n_in,
                              void* d_out, int out_size, void* d_ws, size_t ws_size,
                              hipStream_t stream) {
  const float* q           = (const float*)d_in[0];
  const float* k           = (const float*)d_in[1];
  const float* v           = (const float*)d_in[2];
  const float* mask        = (const float*)d_in[3];
  const float* depth_value = (const float*)d_in[4];
  const float* va_a_mask   = (const float*)d_in[7];
  const float* mean_depth  = (const float*)d_in[8];
  const float* Wq = (const float*)d_in[9];
  const float* bq = (const float*)d_in[10];
  const float* Wk = (const float*)d_in[11];
  const float* bk = (const float*)d_in[12];
  const float* Wv = (const float*)d_in[13];
  const float* bv = (const float*)d_in[14];
  const float* Wo = (const float*)d_in[15];
  const float* bo = (const float*)d_in[16];

  unsigned short* wsu = (unsigned short*)d_ws;
  unsigned short* qh  = wsu;                 // aliased by ctx after q-frag reads
  unsigned short* kh  = wsu + N_QH;
  unsigned short* vhT = wsu + 2 * N_QH;
  unsigned short* ctx = qh;                  // alias (per-row ownership matches)
  unsigned short* wt  = wsu + 3 * N_QH;      // 4 weights x 262144 bf16
  float* md_rows = (float*)(wsu + 3 * N_QH + 4 * 262144);

  float* out       = (float*)d_out;
  float* att_score = out + (size_t)B * S * HD;
  float* att_map   = att_score + (size_t)B * H * S * S;
  float* md_out    = att_map + (size_t)B * H * S * S;

  prep_w<<<256, 256, 0, stream>>>(Wq, Wk, Wv, Wo, wt);
  qkv_mfma<<<1152, 256, 0, stream>>>(q, k, v, wt, bq, bk, bv, qh, kh, vhT);
  fused_attn<<<3072, 256, 0, stream>>>(qh, kh, vhT, mask, depth_value, mean_depth,
                                       att_score, att_map, ctx, md_rows);
  gemm_out<<<776, 256, 0, stream>>>(ctx, wt + 3 * 262144, bo, out,
                                    md_rows, va_a_mask, md_out);
}